// Round 1
// baseline (3663.988 us; speedup 1.0000x reference)
//
#include <hip/hip_runtime.h>
#include <hip/hip_fp16.h>

// NODEModel: fused per-point MLP evaluation, fp32 VALU baseline.
// Each thread = one point. Hidden activations (post-tanh, in [-1,1]) live in a
// thread-private LDS column as fp16 pairs (k-major layout: buf[pair*BLOCK+tid]
// -> byte addr pair*512 + tid*4 -> bank = tid%32, conflict-free).
// Double-buffered columns: 2 * 64 pairs * 128 threads * 4B = 64 KB LDS/block.
// No __syncthreads anywhere (columns are thread-private).
// Weights are wave-uniform addressed -> scalar loads; inner loop is
// 16 v_fma_f32 per ds_read_b32.

#define WIDTH 128
#define BLOCK 128
#define NPAIR (WIDTH / 2)

__device__ __forceinline__ float fast_tanh(float x) {
    // tanh(x) = 1 - 2/(exp(2x)+1); exact limits at +-inf via IEEE semantics.
    float e = __expf(2.0f * x);
    return 1.0f - 2.0f / (e + 1.0f);
}

__device__ __forceinline__ unsigned int pack2(float a, float b) {
    union { __half2 h2; unsigned int u32; } c;
    c.h2 = __floats2half2_rn(a, b);
    return c.u32;
}

__device__ __forceinline__ float2 unpack2(unsigned int u) {
    union { __half2 h2; unsigned int u32; } c;
    c.u32 = u;
    return __half22float2(c.h2);
}

template <int D_IN>
__device__ __forceinline__ float mlp_eval(
    const float* feat,
    const float* __restrict__ Win, const float* __restrict__ bin,
    const float* __restrict__ Wh,  const float* __restrict__ bh,
    const float* __restrict__ Wout, const float* __restrict__ bout,
    unsigned int* buf0, unsigned int* buf1, int tid)
{
    // ---- input layer: feat(D_IN) -> tanh -> buf0 ----
    #pragma unroll 1
    for (int j0 = 0; j0 < WIDTH; j0 += 8) {
        float acc[8];
        #pragma unroll
        for (int jj = 0; jj < 8; ++jj) acc[jj] = bin[j0 + jj];
        #pragma unroll
        for (int k = 0; k < D_IN; ++k) {
            float f = feat[k];
            const float* w = Win + k * WIDTH + j0;
            #pragma unroll
            for (int jj = 0; jj < 8; ++jj) acc[jj] = fmaf(f, w[jj], acc[jj]);
        }
        #pragma unroll
        for (int i = 0; i < 4; ++i) {
            float t0 = fast_tanh(acc[2 * i]);
            float t1 = fast_tanh(acc[2 * i + 1]);
            buf0[(j0 / 2 + i) * BLOCK + tid] = pack2(t0, t1);
        }
    }

    // ---- 3 hidden layers, ping-pong buffers ----
    unsigned int* cur = buf0;
    unsigned int* nxt = buf1;
    #pragma unroll 1
    for (int l = 0; l < 3; ++l) {
        const float* W = Wh + l * WIDTH * WIDTH;
        const float* b = bh + l * WIDTH;
        #pragma unroll 1
        for (int j0 = 0; j0 < WIDTH; j0 += 8) {
            float acc[8];
            #pragma unroll
            for (int jj = 0; jj < 8; ++jj) acc[jj] = b[j0 + jj];
            #pragma unroll 4
            for (int p = 0; p < NPAIR; ++p) {
                float2 f = unpack2(cur[p * BLOCK + tid]);
                // wave-uniform addresses -> scalar loads (s_load_dwordx4)
                const float4* w0 = reinterpret_cast<const float4*>(W + (2 * p) * WIDTH + j0);
                const float4* w1 = reinterpret_cast<const float4*>(W + (2 * p + 1) * WIDTH + j0);
                float4 wa = w0[0], wb = w0[1];
                float4 wc = w1[0], wd = w1[1];
                acc[0] = fmaf(f.x, wa.x, acc[0]);
                acc[1] = fmaf(f.x, wa.y, acc[1]);
                acc[2] = fmaf(f.x, wa.z, acc[2]);
                acc[3] = fmaf(f.x, wa.w, acc[3]);
                acc[4] = fmaf(f.x, wb.x, acc[4]);
                acc[5] = fmaf(f.x, wb.y, acc[5]);
                acc[6] = fmaf(f.x, wb.z, acc[6]);
                acc[7] = fmaf(f.x, wb.w, acc[7]);
                acc[0] = fmaf(f.y, wc.x, acc[0]);
                acc[1] = fmaf(f.y, wc.y, acc[1]);
                acc[2] = fmaf(f.y, wc.z, acc[2]);
                acc[3] = fmaf(f.y, wc.w, acc[3]);
                acc[4] = fmaf(f.y, wd.x, acc[4]);
                acc[5] = fmaf(f.y, wd.y, acc[5]);
                acc[6] = fmaf(f.y, wd.z, acc[6]);
                acc[7] = fmaf(f.y, wd.w, acc[7]);
            }
            #pragma unroll
            for (int i = 0; i < 4; ++i) {
                float t0 = fast_tanh(acc[2 * i]);
                float t1 = fast_tanh(acc[2 * i + 1]);
                nxt[(j0 / 2 + i) * BLOCK + tid] = pack2(t0, t1);
            }
        }
        unsigned int* tmp = cur; cur = nxt; nxt = tmp;
    }

    // ---- output layer: h(128) @ Wout(128) + bout ----
    float a0 = 0.0f, a1 = 0.0f, a2 = 0.0f, a3 = 0.0f;
    #pragma unroll 4
    for (int p = 0; p < NPAIR; p += 2) {
        float2 f0 = unpack2(cur[p * BLOCK + tid]);
        float2 f1 = unpack2(cur[(p + 1) * BLOCK + tid]);
        a0 = fmaf(f0.x, Wout[2 * p], a0);
        a1 = fmaf(f0.y, Wout[2 * p + 1], a1);
        a2 = fmaf(f1.x, Wout[2 * p + 2], a2);
        a3 = fmaf(f1.y, Wout[2 * p + 3], a3);
    }
    return (a0 + a1) + (a2 + a3) + bout[0];
}

__global__ __launch_bounds__(BLOCK)
void node_kernel(const float* __restrict__ tx,
                 const float* __restrict__ dp_Win, const float* __restrict__ dp_bin,
                 const float* __restrict__ dp_Wh,  const float* __restrict__ dp_bh,
                 const float* __restrict__ dp_Wout,const float* __restrict__ dp_bout,
                 const float* __restrict__ ic_Win, const float* __restrict__ ic_bin,
                 const float* __restrict__ ic_Wh,  const float* __restrict__ ic_bh,
                 const float* __restrict__ ic_Wout,const float* __restrict__ ic_bout,
                 float* __restrict__ out, int n)
{
    __shared__ unsigned int hbuf[2][NPAIR * BLOCK];  // 64 KB
    int tid = threadIdx.x;
    int gid = blockIdx.x * BLOCK + tid;
    if (gid >= n) return;

    float4 p = reinterpret_cast<const float4*>(tx)[gid];
    float tf = p.x, xx = p.y, yy = p.z, zz = p.w;
    float r = sqrtf(xx * xx + yy * yy + zz * zz);
    float rs = fmaxf(r, 1e-8f);
    float inv_rs = 1.0f / rs;
    float inv1r = 1.0f / (1.0f + r);
    float ux = xx * inv_rs, uy = yy * inv_rs, uz = zz * inv_rs;
    // Note: min(r, CLIP*max(r)) with CLIP=1.0 is identity -> feat0 = r.

    float feat_ic[5] = { r, ux, uy, uz, inv1r };
    float ic = mlp_eval<5>(feat_ic, ic_Win, ic_bin, ic_Wh, ic_bh, ic_Wout, ic_bout,
                           hbuf[0], hbuf[1], tid);

    float a = 0.5f * tf;  // (tf - T0)/2, T0 = 0
    // t_q = a*node + b = a*(node+1) since b = a when T0=0.
    const float np1[3] = { 0.22540333075851662f, 1.0f, 1.7745966692414834f };
    const float gw[3]  = { 5.0f / 9.0f, 8.0f / 9.0f, 5.0f / 9.0f };
    float dsum = 0.0f;
    #pragma unroll 1
    for (int q = 0; q < 3; ++q) {
        float feat_dp[6] = { a * np1[q], r, ux, uy, uz, inv1r };
        float v = mlp_eval<6>(feat_dp, dp_Win, dp_bin, dp_Wh, dp_bh, dp_Wout, dp_bout,
                              hbuf[0], hbuf[1], tid);
        dsum = fmaf(gw[q], v, dsum);
    }

    out[gid] = (ic + a * dsum) * inv1r;
}

extern "C" void kernel_launch(void* const* d_in, const int* in_sizes, int n_in,
                              void* d_out, int out_size, void* d_ws, size_t ws_size,
                              hipStream_t stream) {
    const float* tx      = (const float*)d_in[0];
    const float* dp_Win  = (const float*)d_in[1];
    const float* dp_bin  = (const float*)d_in[2];
    const float* dp_Wh   = (const float*)d_in[3];
    const float* dp_bh   = (const float*)d_in[4];
    const float* dp_Wout = (const float*)d_in[5];
    const float* dp_bout = (const float*)d_in[6];
    const float* ic_Win  = (const float*)d_in[7];
    const float* ic_bin  = (const float*)d_in[8];
    const float* ic_Wh   = (const float*)d_in[9];
    const float* ic_bh   = (const float*)d_in[10];
    const float* ic_Wout = (const float*)d_in[11];
    const float* ic_bout = (const float*)d_in[12];
    float* out = (float*)d_out;
    int n = in_sizes[0] / 4;
    int grid = (n + BLOCK - 1) / BLOCK;
    node_kernel<<<dim3(grid), dim3(BLOCK), 0, stream>>>(
        tx, dp_Win, dp_bin, dp_Wh, dp_bh, dp_Wout, dp_bout,
        ic_Win, ic_bin, ic_Wh, ic_bh, ic_Wout, ic_bout, out, n);
}

// Round 2
// 309.238 us; speedup vs baseline: 11.8484x; 11.8484x over previous
//
#include <hip/hip_runtime.h>

// NODEModel MFMA fp16 version.
// GEMM orientation per layer: D = A*B with A = W^T (out-feat x in-feat),
// B = H^T (in-feat x sample). C/D lane layout (col=lane&15=sample,
// row=(lane>>4)*4+reg = 4 consecutive feats) packs as ds_write_b64 into
// sample-major H[sample][feat] fp16, which is exactly the B-operand layout
// (8 consecutive k for fixed sample -> ds_read_b128) of the next layer.
// Each wave owns a 32-sample slab of H (reads+writes only its slab -> no
// barrier for H). Weights staged per layer into LDS via global_load_lds in
// fragment-linear order (prep kernel pre-swizzles) -> lane*16 reads,
// conflict-free. H uses 16B-unit XOR swizzle (unit ^ (sample&7)) -> b128
// floor, no padding, LDS = 32KB H + 32KB W = 64KB -> 2 blocks/CU.

#define NTHREADS 256
#define MLP_STRIDE 53248   // fp16 elems per MLP: 4096 WinA + 3*16384 Wh
#define WINA_ELEMS 4096
#define WH_ELEMS 16384

typedef _Float16 f16;
typedef f16 f16x8 __attribute__((ext_vector_type(8)));
typedef f16 f16x4 __attribute__((ext_vector_type(4)));
typedef float f32x4 __attribute__((ext_vector_type(4)));

// ---------------- prep: fp32 weights -> fp16 fragment-linear ----------------
// WinA frag order: [mt(8)][lane(64)][j(8)], A[m=mt*16+(lane&15)][k=(lane>>4)*8+j]
//   k < din: Win[k][m]; k == din: bin[m] (bias slot, B feature = 1); else 0.
// Wh_l frag order: [ks(4)][mt(8)][lane(64)][j(8)], k = ks*32+(lane>>4)*8+j.
__global__ __launch_bounds__(NTHREADS)
void prep_kernel(const float* __restrict__ dp_Win, const float* __restrict__ dp_bin,
                 const float* __restrict__ dp_Wh,
                 const float* __restrict__ ic_Win, const float* __restrict__ ic_bin,
                 const float* __restrict__ ic_Wh,
                 f16* __restrict__ wsw)
{
    int e = blockIdx.x * NTHREADS + threadIdx.x;
    if (e >= 2 * MLP_STRIDE) return;
    int mlp = (e >= MLP_STRIDE) ? 1 : 0;   // 0 = dp, 1 = ic
    int r = e - mlp * MLP_STRIDE;
    const float* Win = mlp ? ic_Win : dp_Win;
    const float* bin = mlp ? ic_bin : dp_bin;
    const float* Wh  = mlp ? ic_Wh  : dp_Wh;
    int din = mlp ? 5 : 6;
    float val;
    if (r < WINA_ELEMS) {
        int mt = r >> 9, lane = (r >> 3) & 63, j = r & 7;
        int m = mt * 16 + (lane & 15);
        int k = ((lane >> 4) << 3) + j;                     // 0..31
        val = (k < din) ? Win[k * 128 + m] : ((k == din) ? bin[m] : 0.0f);
    } else {
        int r2 = r - WINA_ELEMS;
        int l = r2 >> 14, r3 = r2 & 16383;
        int ks = r3 >> 12, mt = (r3 >> 9) & 7, lane = (r3 >> 3) & 63, j = r3 & 7;
        int m = mt * 16 + (lane & 15);
        int k = ks * 32 + ((lane >> 4) << 3) + j;           // 0..127
        val = Wh[(l * 128 + k) * 128 + m];
    }
    wsw[e] = (f16)val;
}

// ---------------- main ----------------
__device__ __forceinline__ float tanh_fast(float x) {
    float e = __expf(2.0f * x);
    float r = __builtin_amdgcn_rcpf(e + 1.0f);
    return fmaf(-2.0f, r, 1.0f);            // exact +-1 limits via inf/0
}

// XOR-swizzled H address: n = sample 0..127, kb = feat byte offset 0..255.
__device__ __forceinline__ int h_addr(int n, int kb) {
    return n * 256 + ((((kb >> 4) ^ (n & 7)) << 4) | (kb & 15));
}

__device__ __forceinline__ f32x4 mfma16(f16x8 a, f16x8 b, f32x4 c) {
    return __builtin_amdgcn_mfma_f32_16x16x32_f16(a, b, c, 0, 0, 0);
}

__device__ __forceinline__ void stage16(const void* g, void* l) {
    __builtin_amdgcn_global_load_lds((const __attribute__((address_space(1))) void*)g,
                                     (__attribute__((address_space(3))) void*)l, 16, 0, 0);
}

__global__ __launch_bounds__(NTHREADS, 2)
void node_main(const float* __restrict__ tx, const f16* __restrict__ wsw,
               const float* __restrict__ dp_bh, const float* __restrict__ dp_Wout,
               const float* __restrict__ dp_bout,
               const float* __restrict__ ic_bh, const float* __restrict__ ic_Wout,
               const float* __restrict__ ic_bout,
               float* __restrict__ out)
{
    __shared__ __align__(16) unsigned char lds_h[32768];
    __shared__ __align__(16) unsigned char lds_w[32768];

    const int tid  = threadIdx.x;
    const int lane = tid & 63;
    const int wv   = tid >> 6;
    const int q    = lane >> 4;
    const int l15  = lane & 15;
    const int p0   = blockIdx.x * 128;
    const int n0   = wv * 32 + l15;      // sample for nt-half 0 (B-frag col)

    const float4* tx4 = (const float4*)tx;
    // features for B-frag build (meaningful in lanes 0..15, computed by all)
    float4 t0v = tx4[p0 + n0];
    float4 t1v = tx4[p0 + n0 + 16];
    // own-sample scalars for the final combine (thread tid -> sample tid>>1)
    float4 tov = tx4[p0 + (tid >> 1)];

    float a0, r0, x0, y0, z0, i0;
    float a1, r1, x1, y1, z1, i1;
    float ao, io;
    {
        float xx = t0v.y, yy = t0v.z, zz = t0v.w;
        r0 = sqrtf(fmaf(xx, xx, fmaf(yy, yy, zz * zz)));
        float irs = 1.0f / fmaxf(r0, 1e-8f);
        x0 = xx * irs; y0 = yy * irs; z0 = zz * irs;
        i0 = 1.0f / (1.0f + r0);
        a0 = 0.5f * t0v.x;
    }
    {
        float xx = t1v.y, yy = t1v.z, zz = t1v.w;
        r1 = sqrtf(fmaf(xx, xx, fmaf(yy, yy, zz * zz)));
        float irs = 1.0f / fmaxf(r1, 1e-8f);
        x1 = xx * irs; y1 = yy * irs; z1 = zz * irs;
        i1 = 1.0f / (1.0f + r1);
        a1 = 0.5f * t1v.x;
    }
    {
        float xx = tov.y, yy = tov.z, zz = tov.w;
        float rr = sqrtf(fmaf(xx, xx, fmaf(yy, yy, zz * zz)));
        io = 1.0f / (1.0f + rr);
        ao = 0.5f * tov.x;
    }

    float icv = 0.0f, dsum = 0.0f;

    for (int c = 0; c < 4; ++c) {        // c=0: ic MLP; c=1..3: dp at GL node c-1
        const f16* wb       = wsw + (c == 0 ? MLP_STRIDE : 0);
        const float* bh     = (c == 0) ? ic_bh   : dp_bh;
        const float* Wout   = (c == 0) ? ic_Wout : dp_Wout;
        const float* bout   = (c == 0) ? ic_bout : dp_bout;
        const float tn = (c == 1) ? 0.22540333075851662f
                       : ((c == 2) ? 1.0f : 1.7745966692414834f);   // node+1

        // ---- stage WinA (8 KB) ----
        __syncthreads();                  // prior users of lds_w done
        {
            const char* g = (const char*)wb;
            stage16(g + tid * 16, lds_w + tid * 16);
            stage16(g + 4096 + tid * 16, lds_w + 4096 + tid * 16);
        }
        __syncthreads();

        // ---- input layer: B frags from feature registers (lanes 0..15) ----
        f16x8 b0 = {}, b1 = {};
        if (lane < 16) {
            if (c == 0) {
                b0[0] = (f16)r0; b0[1] = (f16)x0; b0[2] = (f16)y0; b0[3] = (f16)z0;
                b0[4] = (f16)i0; b0[5] = (f16)1.0f;
                b1[0] = (f16)r1; b1[1] = (f16)x1; b1[2] = (f16)y1; b1[3] = (f16)z1;
                b1[4] = (f16)i1; b1[5] = (f16)1.0f;
            } else {
                b0[0] = (f16)(a0 * tn); b0[1] = (f16)r0; b0[2] = (f16)x0; b0[3] = (f16)y0;
                b0[4] = (f16)z0; b0[5] = (f16)i0; b0[6] = (f16)1.0f;
                b1[0] = (f16)(a1 * tn); b1[1] = (f16)r1; b1[2] = (f16)x1; b1[3] = (f16)y1;
                b1[4] = (f16)z1; b1[5] = (f16)i1; b1[6] = (f16)1.0f;
            }
        }

        f32x4 acc[8][2];
        #pragma unroll
        for (int mt = 0; mt < 8; ++mt) {
            acc[mt][0] = (f32x4){0.f, 0.f, 0.f, 0.f};
            acc[mt][1] = (f32x4){0.f, 0.f, 0.f, 0.f};
        }
        #pragma unroll
        for (int mt = 0; mt < 8; ++mt) {
            f16x8 a = *(const f16x8*)(lds_w + ((mt * 64 + lane) << 4));
            acc[mt][0] = mfma16(a, b0, acc[mt][0]);
            acc[mt][1] = mfma16(a, b1, acc[mt][1]);
        }
        #pragma unroll
        for (int mt = 0; mt < 8; ++mt) {      // bin folded into WinA k=din slot
            #pragma unroll
            for (int hh = 0; hh < 2; ++hh) {
                f16x4 o;
                o[0] = (f16)tanh_fast(acc[mt][hh][0]);
                o[1] = (f16)tanh_fast(acc[mt][hh][1]);
                o[2] = (f16)tanh_fast(acc[mt][hh][2]);
                o[3] = (f16)tanh_fast(acc[mt][hh][3]);
                *(f16x4*)(lds_h + h_addr(n0 + hh * 16, mt * 32 + q * 8)) = o;
            }
        }

        // ---- 3 hidden layers ----
        for (int l = 0; l < 3; ++l) {
            __syncthreads();              // all waves done reading lds_w
            {
                const char* g = (const char*)(wb + WINA_ELEMS + l * WH_ELEMS);
                #pragma unroll
                for (int it = 0; it < 8; ++it)
                    stage16(g + it * 4096 + tid * 16, lds_w + it * 4096 + tid * 16);
            }
            __syncthreads();              // staged (vmcnt drained by barrier)

            #pragma unroll
            for (int mt = 0; mt < 8; ++mt) {
                acc[mt][0] = (f32x4){0.f, 0.f, 0.f, 0.f};
                acc[mt][1] = (f32x4){0.f, 0.f, 0.f, 0.f};
            }
            #pragma unroll
            for (int ks = 0; ks < 4; ++ks) {
                f16x8 hb0 = *(const f16x8*)(lds_h + h_addr(n0,      ks * 64 + q * 16));
                f16x8 hb1 = *(const f16x8*)(lds_h + h_addr(n0 + 16, ks * 64 + q * 16));
                #pragma unroll
                for (int mt = 0; mt < 8; ++mt) {
                    f16x8 a = *(const f16x8*)(lds_w + (((ks * 8 + mt) * 64 + lane) << 4));
                    acc[mt][0] = mfma16(a, hb0, acc[mt][0]);
                    acc[mt][1] = mfma16(a, hb1, acc[mt][1]);
                }
            }
            #pragma unroll
            for (int mt = 0; mt < 8; ++mt) {
                f32x4 bv = *(const f32x4*)(bh + l * 128 + mt * 16 + q * 4);
                #pragma unroll
                for (int hh = 0; hh < 2; ++hh) {
                    f16x4 o;
                    o[0] = (f16)tanh_fast(acc[mt][hh][0] + bv[0]);
                    o[1] = (f16)tanh_fast(acc[mt][hh][1] + bv[1]);
                    o[2] = (f16)tanh_fast(acc[mt][hh][2] + bv[2]);
                    o[3] = (f16)tanh_fast(acc[mt][hh][3] + bv[3]);
                    *(f16x4*)(lds_h + h_addr(n0 + hh * 16, mt * 32 + q * 8)) = o;
                }
            }
        }

        // ---- output layer: VALU dot, 2 threads per sample ----
        __syncthreads();                  // cross-lane H visibility
        {
            int s  = tid >> 1;
            int hf = tid & 1;
            const float* wp = Wout + hf * 64;
            float sum = 0.0f;
            #pragma unroll
            for (int u = 0; u < 8; ++u) {
                f16x8 hv = *(const f16x8*)(lds_h + h_addr(s, hf * 128 + u * 16));
                f32x4 w0 = *(const f32x4*)(wp + u * 8);
                f32x4 w1 = *(const f32x4*)(wp + u * 8 + 4);
                sum = fmaf((float)hv[0], w0[0], sum);
                sum = fmaf((float)hv[1], w0[1], sum);
                sum = fmaf((float)hv[2], w0[2], sum);
                sum = fmaf((float)hv[3], w0[3], sum);
                sum = fmaf((float)hv[4], w1[0], sum);
                sum = fmaf((float)hv[5], w1[1], sum);
                sum = fmaf((float)hv[6], w1[2], sum);
                sum = fmaf((float)hv[7], w1[3], sum);
            }
            sum += __shfl_xor(sum, 1, 64);
            float val = sum + bout[0];
            if (c == 0) icv = val;
            else        dsum = fmaf((c == 2) ? (8.0f / 9.0f) : (5.0f / 9.0f), val, dsum);
        }
    }

    if ((tid & 1) == 0) {
        out[p0 + (tid >> 1)] = (icv + ao * dsum) * io;
    }
}

extern "C" void kernel_launch(void* const* d_in, const int* in_sizes, int n_in,
                              void* d_out, int out_size, void* d_ws, size_t ws_size,
                              hipStream_t stream) {
    const float* tx      = (const float*)d_in[0];
    const float* dp_Win  = (const float*)d_in[1];
    const float* dp_bin  = (const float*)d_in[2];
    const float* dp_Wh   = (const float*)d_in[3];
    const float* dp_bh   = (const float*)d_in[4];
    const float* dp_Wout = (const float*)d_in[5];
    const float* dp_bout = (const float*)d_in[6];
    const float* ic_Win  = (const float*)d_in[7];
    const float* ic_bin  = (const float*)d_in[8];
    const float* ic_Wh   = (const float*)d_in[9];
    const float* ic_bh   = (const float*)d_in[10];
    const float* ic_Wout = (const float*)d_in[11];
    const float* ic_bout = (const float*)d_in[12];
    float* out = (float*)d_out;
    f16* wsw = (f16*)d_ws;

    int n = in_sizes[0] / 4;

    prep_kernel<<<dim3((2 * MLP_STRIDE + NTHREADS - 1) / NTHREADS), dim3(NTHREADS), 0, stream>>>(
        dp_Win, dp_bin, dp_Wh, ic_Win, ic_bin, ic_Wh, wsw);

    node_main<<<dim3(n / 128), dim3(NTHREADS), 0, stream>>>(
        tx, wsw, dp_bh, dp_Wout, dp_bout, ic_bh, ic_Wout, ic_bout, out);
}

// Round 4
// 275.758 us; speedup vs baseline: 13.2870x; 1.1214x over previous
//
#include <hip/hip_runtime.h>

// NODEModel MFMA fp16, R4 = R3 with the cvt_pkrtz type fixed.
// - All H LDS addresses (XOR-swizzled) precomputed once per thread; hh-half
//   selected via +4096 byte immediate (folds into ds offset field).
// - Hidden-layer bias rides in as the C operand of the ks=0 MFMA.
// - f16 packing via v_cvt_pkrtz (2 f32 -> 1 packed reg in one instr).
// - tanh: exp2(x*2log2e) form -> mul, exp, add, rcp, fma (no double mul).
// Layout identical to R2: A = W^T fragment-linear in lds_w (prep kernel
// pre-swizzles), H sample-major f16 with 16B-unit XOR swizzle in lds_h.

#define NTHREADS 256
#define MLP_STRIDE 53248   // fp16 elems per MLP: 4096 WinA + 3*16384 Wh
#define WINA_ELEMS 4096
#define WH_ELEMS 16384

typedef _Float16 f16;
typedef f16 f16x8 __attribute__((ext_vector_type(8)));
typedef __fp16 fp16x2 __attribute__((ext_vector_type(2)));
typedef float f32x4 __attribute__((ext_vector_type(4)));

// ---------------- prep: fp32 weights -> fp16 fragment-linear ----------------
__global__ __launch_bounds__(NTHREADS)
void prep_kernel(const float* __restrict__ dp_Win, const float* __restrict__ dp_bin,
                 const float* __restrict__ dp_Wh,
                 const float* __restrict__ ic_Win, const float* __restrict__ ic_bin,
                 const float* __restrict__ ic_Wh,
                 f16* __restrict__ wsw)
{
    int e = blockIdx.x * NTHREADS + threadIdx.x;
    if (e >= 2 * MLP_STRIDE) return;
    int mlp = (e >= MLP_STRIDE) ? 1 : 0;   // 0 = dp, 1 = ic
    int r = e - mlp * MLP_STRIDE;
    const float* Win = mlp ? ic_Win : dp_Win;
    const float* bin = mlp ? ic_bin : dp_bin;
    const float* Wh  = mlp ? ic_Wh  : dp_Wh;
    int din = mlp ? 5 : 6;
    float val;
    if (r < WINA_ELEMS) {
        int mt = r >> 9, lane = (r >> 3) & 63, j = r & 7;
        int m = mt * 16 + (lane & 15);
        int k = ((lane >> 4) << 3) + j;                     // 0..31
        val = (k < din) ? Win[k * 128 + m] : ((k == din) ? bin[m] : 0.0f);
    } else {
        int r2 = r - WINA_ELEMS;
        int l = r2 >> 14, r3 = r2 & 16383;
        int ks = r3 >> 12, mt = (r3 >> 9) & 7, lane = (r3 >> 3) & 63, j = r3 & 7;
        int m = mt * 16 + (lane & 15);
        int k = ks * 32 + ((lane >> 4) << 3) + j;           // 0..127
        val = Wh[(l * 128 + k) * 128 + m];
    }
    wsw[e] = (f16)val;
}

// ---------------- main ----------------
__device__ __forceinline__ float tanh_fast(float x) {
    // tanh(x) = 1 - 2/(exp2(2*log2e*x)+1); mul, exp(trans), add, rcp(trans), fma
    float e = __builtin_amdgcn_exp2f(x * 2.8853900817779268f);
    float r = __builtin_amdgcn_rcpf(e + 1.0f);
    return fmaf(-2.0f, r, 1.0f);
}

__device__ __forceinline__ unsigned int pk16(float a, float b) {
    union { fp16x2 h; unsigned int u; } c;
    c.h = __builtin_amdgcn_cvt_pkrtz(a, b);
    return c.u;
}

// XOR-swizzled H address (used only in the small output-layer section).
__device__ __forceinline__ int h_addr(int n, int kb) {
    return n * 256 + ((((kb >> 4) ^ (n & 7)) << 4) | (kb & 15));
}

__device__ __forceinline__ f32x4 mfma16(f16x8 a, f16x8 b, f32x4 c) {
    return __builtin_amdgcn_mfma_f32_16x16x32_f16(a, b, c, 0, 0, 0);
}

__device__ __forceinline__ void stage16(const void* g, void* l) {
    __builtin_amdgcn_global_load_lds((const __attribute__((address_space(1))) void*)g,
                                     (__attribute__((address_space(3))) void*)l, 16, 0, 0);
}

__global__ __launch_bounds__(NTHREADS, 2)
void node_main(const float* __restrict__ tx, const f16* __restrict__ wsw,
               const float* __restrict__ dp_bh, const float* __restrict__ dp_Wout,
               const float* __restrict__ dp_bout,
               const float* __restrict__ ic_bh, const float* __restrict__ ic_Wout,
               const float* __restrict__ ic_bout,
               float* __restrict__ out)
{
    __shared__ __align__(16) unsigned char lds_h[32768];
    __shared__ __align__(16) unsigned char lds_w[32768];

    const int tid  = threadIdx.x;
    const int lane = tid & 63;
    const int wv   = tid >> 6;
    const int q    = lane >> 4;
    const int l15  = lane & 15;
    const int p0   = blockIdx.x * 128;
    const int n0   = wv * 32 + l15;      // sample for hh-half 0 (B-frag col)

    // ---- precomputed, chain/layer-invariant LDS addresses ----
    const int d   = l15 & 7;             // XOR key (row n0 and n0+16 share it)
    const int e2  = q >> 1;
    const int par = (q & 1) << 3;
    int waddr[8];                        // H write base, feat-tile mt, hh=0
    #pragma unroll
    for (int mt = 0; mt < 8; ++mt)
        waddr[mt] = n0 * 256 + ((((2 * mt + e2) ^ d) << 4) | par);
    int raddr[4];                        // H read base, k-slab ks, hh=0
    #pragma unroll
    for (int ks = 0; ks < 4; ++ks)
        raddr[ks] = n0 * 256 + (((4 * ks + q) ^ d) << 4);

    const float4* tx4 = (const float4*)tx;
    float4 t0v = tx4[p0 + n0];
    float4 t1v = tx4[p0 + n0 + 16];
    float4 tov = tx4[p0 + (tid >> 1)];

    float a0, r0, x0, y0, z0, i0;
    float a1, r1, x1, y1, z1, i1;
    float ao, io;
    {
        float xx = t0v.y, yy = t0v.z, zz = t0v.w;
        r0 = sqrtf(fmaf(xx, xx, fmaf(yy, yy, zz * zz)));
        float irs = 1.0f / fmaxf(r0, 1e-8f);
        x0 = xx * irs; y0 = yy * irs; z0 = zz * irs;
        i0 = 1.0f / (1.0f + r0);
        a0 = 0.5f * t0v.x;
    }
    {
        float xx = t1v.y, yy = t1v.z, zz = t1v.w;
        r1 = sqrtf(fmaf(xx, xx, fmaf(yy, yy, zz * zz)));
        float irs = 1.0f / fmaxf(r1, 1e-8f);
        x1 = xx * irs; y1 = yy * irs; z1 = zz * irs;
        i1 = 1.0f / (1.0f + r1);
        a1 = 0.5f * t1v.x;
    }
    {
        float xx = tov.y, yy = tov.z, zz = tov.w;
        float rr = sqrtf(fmaf(xx, xx, fmaf(yy, yy, zz * zz)));
        io = 1.0f / (1.0f + rr);
        ao = 0.5f * tov.x;
    }

    const f32x4 z4 = {0.f, 0.f, 0.f, 0.f};
    float icv = 0.0f, dsum = 0.0f;

    for (int c = 0; c < 4; ++c) {        // c=0: ic MLP; c=1..3: dp at GL node c-1
        const f16* wb       = wsw + (c == 0 ? MLP_STRIDE : 0);
        const float* bh     = (c == 0) ? ic_bh   : dp_bh;
        const float* Wout   = (c == 0) ? ic_Wout : dp_Wout;
        const float* bout   = (c == 0) ? ic_bout : dp_bout;
        const float tn = (c == 1) ? 0.22540333075851662f
                       : ((c == 2) ? 1.0f : 1.7745966692414834f);   // node+1

        // ---- stage WinA (8 KB) ----
        __syncthreads();                  // prior users of lds_w done
        {
            const char* g = (const char*)wb;
            stage16(g + tid * 16, lds_w + tid * 16);
            stage16(g + 4096 + tid * 16, lds_w + 4096 + tid * 16);
        }
        __syncthreads();

        // ---- input layer: B frags from feature registers (lanes 0..15) ----
        f16x8 b0 = {}, b1 = {};
        if (lane < 16) {
            if (c == 0) {
                b0[0] = (f16)r0; b0[1] = (f16)x0; b0[2] = (f16)y0; b0[3] = (f16)z0;
                b0[4] = (f16)i0; b0[5] = (f16)1.0f;
                b1[0] = (f16)r1; b1[1] = (f16)x1; b1[2] = (f16)y1; b1[3] = (f16)z1;
                b1[4] = (f16)i1; b1[5] = (f16)1.0f;
            } else {
                b0[0] = (f16)(a0 * tn); b0[1] = (f16)r0; b0[2] = (f16)x0; b0[3] = (f16)y0;
                b0[4] = (f16)z0; b0[5] = (f16)i0; b0[6] = (f16)1.0f;
                b1[0] = (f16)(a1 * tn); b1[1] = (f16)r1; b1[2] = (f16)x1; b1[3] = (f16)y1;
                b1[4] = (f16)z1; b1[5] = (f16)i1; b1[6] = (f16)1.0f;
            }
        }

        f32x4 acc[8][2];
        #pragma unroll
        for (int mt = 0; mt < 8; ++mt) {
            f16x8 a = *(const f16x8*)(lds_w + ((mt * 64 + lane) << 4));
            acc[mt][0] = mfma16(a, b0, z4);      // bin folded into A k=din slot
            acc[mt][1] = mfma16(a, b1, z4);
        }
        #pragma unroll
        for (int mt = 0; mt < 8; ++mt) {
            #pragma unroll
            for (int hh = 0; hh < 2; ++hh) {
                f32x4 v = acc[mt][hh];
                uint2 o;
                o.x = pk16(tanh_fast(v[0]), tanh_fast(v[1]));
                o.y = pk16(tanh_fast(v[2]), tanh_fast(v[3]));
                *(uint2*)(lds_h + waddr[mt] + hh * 4096) = o;
            }
        }

        // ---- 3 hidden layers ----
        for (int l = 0; l < 3; ++l) {
            __syncthreads();              // all waves done reading lds_w
            f32x4 bias4[8];
            {
                const char* g = (const char*)(wb + WINA_ELEMS + l * WH_ELEMS);
                #pragma unroll
                for (int it = 0; it < 8; ++it)
                    stage16(g + it * 4096 + tid * 16, lds_w + it * 4096 + tid * 16);
                // bias loads complete during the barrier's vmcnt drain
                #pragma unroll
                for (int mt = 0; mt < 8; ++mt)
                    bias4[mt] = *(const f32x4*)(bh + l * 128 + mt * 16 + q * 4);
            }
            __syncthreads();              // staged + H visible

            #pragma unroll
            for (int ks = 0; ks < 4; ++ks) {
                f16x8 hb0 = *(const f16x8*)(lds_h + raddr[ks]);
                f16x8 hb1 = *(const f16x8*)(lds_h + raddr[ks] + 4096);
                #pragma unroll
                for (int mt = 0; mt < 8; ++mt) {
                    f16x8 a = *(const f16x8*)(lds_w + (((ks * 8 + mt) * 64 + lane) << 4));
                    if (ks == 0) {
                        acc[mt][0] = mfma16(a, hb0, bias4[mt]);  // bias as C-init
                        acc[mt][1] = mfma16(a, hb1, bias4[mt]);
                    } else {
                        acc[mt][0] = mfma16(a, hb0, acc[mt][0]);
                        acc[mt][1] = mfma16(a, hb1, acc[mt][1]);
                    }
                }
            }
            #pragma unroll
            for (int mt = 0; mt < 8; ++mt) {
                #pragma unroll
                for (int hh = 0; hh < 2; ++hh) {
                    f32x4 v = acc[mt][hh];
                    uint2 o;
                    o.x = pk16(tanh_fast(v[0]), tanh_fast(v[1]));
                    o.y = pk16(tanh_fast(v[2]), tanh_fast(v[3]));
                    *(uint2*)(lds_h + waddr[mt] + hh * 4096) = o;
                }
            }
        }

        // ---- output layer: VALU dot, 2 threads per sample ----
        __syncthreads();                  // cross-lane H visibility
        {
            int s  = tid >> 1;
            int hf = tid & 1;
            const float* wp = Wout + hf * 64;
            float sum = 0.0f;
            #pragma unroll
            for (int u = 0; u < 8; ++u) {
                f16x8 hv = *(const f16x8*)(lds_h + h_addr(s, hf * 128 + u * 16));
                f32x4 w0 = *(const f32x4*)(wp + u * 8);
                f32x4 w1 = *(const f32x4*)(wp + u * 8 + 4);
                sum = fmaf((float)hv[0], w0[0], sum);
                sum = fmaf((float)hv[1], w0[1], sum);
                sum = fmaf((float)hv[2], w0[2], sum);
                sum = fmaf((float)hv[3], w0[3], sum);
                sum = fmaf((float)hv[4], w1[0], sum);
                sum = fmaf((float)hv[5], w1[1], sum);
                sum = fmaf((float)hv[6], w1[2], sum);
                sum = fmaf((float)hv[7], w1[3], sum);
            }
            sum += __shfl_xor(sum, 1, 64);
            float val = sum + bout[0];
            if (c == 0) icv = val;
            else        dsum = fmaf((c == 2) ? (8.0f / 9.0f) : (5.0f / 9.0f), val, dsum);
        }
    }

    if ((tid & 1) == 0) {
        out[p0 + (tid >> 1)] = (icv + ao * dsum) * io;
    }
}

extern "C" void kernel_launch(void* const* d_in, const int* in_sizes, int n_in,
                              void* d_out, int out_size, void* d_ws, size_t ws_size,
                              hipStream_t stream) {
    const float* tx      = (const float*)d_in[0];
    const float* dp_Win  = (const float*)d_in[1];
    const float* dp_bin  = (const float*)d_in[2];
    const float* dp_Wh   = (const float*)d_in[3];
    const float* dp_bh   = (const float*)d_in[4];
    const float* dp_Wout = (const float*)d_in[5];
    const float* dp_bout = (const float*)d_in[6];
    const float* ic_Win  = (const float*)d_in[7];
    const float* ic_bin  = (const float*)d_in[8];
    const float* ic_Wh   = (const float*)d_in[9];
    const float* ic_bh   = (const float*)d_in[10];
    const float* ic_Wout = (const float*)d_in[11];
    const float* ic_bout = (const float*)d_in[12];
    float* out = (float*)d_out;
    f16* wsw = (f16*)d_ws;

    int n = in_sizes[0] / 4;

    prep_kernel<<<dim3((2 * MLP_STRIDE + NTHREADS - 1) / NTHREADS), dim3(NTHREADS), 0, stream>>>(
        dp_Win, dp_bin, dp_Wh, ic_Win, ic_bin, ic_Wh, wsw);

    node_main<<<dim3(n / 128), dim3(NTHREADS), 0, stream>>>(
        tx, wsw, dp_bh, dp_Wout, dp_bout, ic_bh, ic_Wout, ic_bout, out);
}

// Round 5
// 249.241 us; speedup vs baseline: 14.7006x; 1.1064x over previous
//
#include <hip/hip_runtime.h>

// NODEModel MFMA fp16, R5: occupancy push.
// - lds_w shrunk 32KB -> 16KB: hidden layers staged in two ks-halves.
//   LDS total = 32KB H + 16KB W = 48KB -> 3 blocks/CU (was 2).
// - tanh input scale 2*log2e folded into Win/bin/Wh/bh by prep kernel
//   (scaled biases in fp32 workspace region); tanh = exp2, add, rcp, fma.
// - Otherwise identical to R4: A = W^T fragment-linear (prep pre-swizzles),
//   H sample-major f16 with 16B-unit XOR swizzle, bias as MFMA C-init,
//   v_cvt_pkrtz packing, precomputed H addresses.

#define NTHREADS 256
#define MLP_STRIDE 53248   // fp16 elems per MLP: 4096 WinA + 3*16384 Wh
#define WINA_ELEMS 4096
#define WH_ELEMS 16384
#define TANH_SCALE 2.8853900817779268f   // 2*log2(e)

typedef _Float16 f16;
typedef f16 f16x8 __attribute__((ext_vector_type(8)));
typedef __fp16 fp16x2 __attribute__((ext_vector_type(2)));
typedef float f32x4 __attribute__((ext_vector_type(4)));

// ---------------- prep: fp32 weights -> fp16 fragment-linear (pre-scaled) ----
// Also writes 2*log2e-scaled hidden biases as fp32 at wsw + 2*MLP_STRIDE.
__global__ __launch_bounds__(NTHREADS)
void prep_kernel(const float* __restrict__ dp_Win, const float* __restrict__ dp_bin,
                 const float* __restrict__ dp_Wh,  const float* __restrict__ dp_bh,
                 const float* __restrict__ ic_Win, const float* __restrict__ ic_bin,
                 const float* __restrict__ ic_Wh,  const float* __restrict__ ic_bh,
                 f16* __restrict__ wsw)
{
    int e = blockIdx.x * NTHREADS + threadIdx.x;
    if (e >= 2 * MLP_STRIDE + 768) return;
    if (e >= 2 * MLP_STRIDE) {          // scaled hidden biases, fp32
        int idx = e - 2 * MLP_STRIDE;   // [mlp(2)][l(3)][m(128)]
        int mlp = idx / 384, rem = idx % 384;
        const float* bh = mlp ? ic_bh : dp_bh;
        float* bsc = (float*)(wsw + 2 * MLP_STRIDE);
        bsc[idx] = bh[rem] * TANH_SCALE;
        return;
    }
    int mlp = (e >= MLP_STRIDE) ? 1 : 0;   // 0 = dp, 1 = ic
    int r = e - mlp * MLP_STRIDE;
    const float* Win = mlp ? ic_Win : dp_Win;
    const float* bin = mlp ? ic_bin : dp_bin;
    const float* Wh  = mlp ? ic_Wh  : dp_Wh;
    int din = mlp ? 5 : 6;
    float val;
    if (r < WINA_ELEMS) {
        int mt = r >> 9, lane = (r >> 3) & 63, j = r & 7;
        int m = mt * 16 + (lane & 15);
        int k = ((lane >> 4) << 3) + j;                     // 0..31
        val = (k < din) ? Win[k * 128 + m] : ((k == din) ? bin[m] : 0.0f);
    } else {
        int r2 = r - WINA_ELEMS;
        int l = r2 >> 14, r3 = r2 & 16383;
        int ks = r3 >> 12, mt = (r3 >> 9) & 7, lane = (r3 >> 3) & 63, j = r3 & 7;
        int m = mt * 16 + (lane & 15);
        int k = ks * 32 + ((lane >> 4) << 3) + j;           // 0..127
        val = Wh[(l * 128 + k) * 128 + m];
    }
    wsw[e] = (f16)(val * TANH_SCALE);
}

// ---------------- main ----------------
__device__ __forceinline__ float tanh_fast(float x) {
    // input pre-scaled by 2*log2e: tanh = 1 - 2/(exp2(x)+1)
    float e = __builtin_amdgcn_exp2f(x);
    float r = __builtin_amdgcn_rcpf(e + 1.0f);
    return fmaf(-2.0f, r, 1.0f);
}

__device__ __forceinline__ unsigned int pk16(float a, float b) {
    union { fp16x2 h; unsigned int u; } c;
    c.h = __builtin_amdgcn_cvt_pkrtz(a, b);
    return c.u;
}

// XOR-swizzled H address (used only in the small output-layer section).
__device__ __forceinline__ int h_addr(int n, int kb) {
    return n * 256 + ((((kb >> 4) ^ (n & 7)) << 4) | (kb & 15));
}

__device__ __forceinline__ f32x4 mfma16(f16x8 a, f16x8 b, f32x4 c) {
    return __builtin_amdgcn_mfma_f32_16x16x32_f16(a, b, c, 0, 0, 0);
}

__device__ __forceinline__ void stage16(const void* g, void* l) {
    __builtin_amdgcn_global_load_lds((const __attribute__((address_space(1))) void*)g,
                                     (__attribute__((address_space(3))) void*)l, 16, 0, 0);
}

__global__ __launch_bounds__(NTHREADS, 3)
void node_main(const float* __restrict__ tx, const f16* __restrict__ wsw,
               const float* __restrict__ dp_Wout, const float* __restrict__ dp_bout,
               const float* __restrict__ ic_Wout, const float* __restrict__ ic_bout,
               float* __restrict__ out)
{
    __shared__ __align__(16) unsigned char lds_h[32768];
    __shared__ __align__(16) unsigned char lds_w[16384];

    const int tid  = threadIdx.x;
    const int lane = tid & 63;
    const int wv   = tid >> 6;
    const int q    = lane >> 4;
    const int l15  = lane & 15;
    const int p0   = blockIdx.x * 128;
    const int n0   = wv * 32 + l15;      // sample for hh-half 0 (B-frag col)

    // ---- precomputed, chain/layer-invariant LDS addresses ----
    const int d   = l15 & 7;             // XOR key (row n0 and n0+16 share it)
    const int e2  = q >> 1;
    const int par = (q & 1) << 3;
    int waddr[8];                        // H write base, feat-tile mt, hh=0
    #pragma unroll
    for (int mt = 0; mt < 8; ++mt)
        waddr[mt] = n0 * 256 + ((((2 * mt + e2) ^ d) << 4) | par);
    int raddr[4];                        // H read base, k-slab ks, hh=0
    #pragma unroll
    for (int ks = 0; ks < 4; ++ks)
        raddr[ks] = n0 * 256 + (((4 * ks + q) ^ d) << 4);

    const float* bsc = (const float*)(wsw + 2 * MLP_STRIDE);  // scaled biases

    const float4* tx4 = (const float4*)tx;
    float4 t0v = tx4[p0 + n0];
    float4 t1v = tx4[p0 + n0 + 16];
    float4 tov = tx4[p0 + (tid >> 1)];

    float a0, r0, x0, y0, z0, i0;
    float a1, r1, x1, y1, z1, i1;
    float ao, io;
    {
        float xx = t0v.y, yy = t0v.z, zz = t0v.w;
        r0 = sqrtf(fmaf(xx, xx, fmaf(yy, yy, zz * zz)));
        float irs = 1.0f / fmaxf(r0, 1e-8f);
        x0 = xx * irs; y0 = yy * irs; z0 = zz * irs;
        i0 = 1.0f / (1.0f + r0);
        a0 = 0.5f * t0v.x;
    }
    {
        float xx = t1v.y, yy = t1v.z, zz = t1v.w;
        r1 = sqrtf(fmaf(xx, xx, fmaf(yy, yy, zz * zz)));
        float irs = 1.0f / fmaxf(r1, 1e-8f);
        x1 = xx * irs; y1 = yy * irs; z1 = zz * irs;
        i1 = 1.0f / (1.0f + r1);
        a1 = 0.5f * t1v.x;
    }
    {
        float xx = tov.y, yy = tov.z, zz = tov.w;
        float rr = sqrtf(fmaf(xx, xx, fmaf(yy, yy, zz * zz)));
        io = 1.0f / (1.0f + rr);
        ao = 0.5f * tov.x;
    }

    const f32x4 z4 = {0.f, 0.f, 0.f, 0.f};
    float icv = 0.0f, dsum = 0.0f;

    for (int c = 0; c < 4; ++c) {        // c=0: ic MLP; c=1..3: dp at GL node c-1
        const f16* wb       = wsw + (c == 0 ? MLP_STRIDE : 0);
        const float* bb     = bsc + (c == 0 ? 384 : 0);
        const float* Wout   = (c == 0) ? ic_Wout : dp_Wout;
        const float* bout   = (c == 0) ? ic_bout : dp_bout;
        const float tn = (c == 1) ? 0.22540333075851662f
                       : ((c == 2) ? 1.0f : 1.7745966692414834f);   // node+1

        // ---- stage WinA (8 KB) ----
        __syncthreads();                  // prior users of lds_w done
        {
            const char* g = (const char*)wb;
            stage16(g + tid * 16, lds_w + tid * 16);
            stage16(g + 4096 + tid * 16, lds_w + 4096 + tid * 16);
        }
        __syncthreads();

        // ---- input layer: B frags from feature registers (lanes 0..15) ----
        f16x8 b0 = {}, b1 = {};
        if (lane < 16) {
            if (c == 0) {
                b0[0] = (f16)r0; b0[1] = (f16)x0; b0[2] = (f16)y0; b0[3] = (f16)z0;
                b0[4] = (f16)i0; b0[5] = (f16)1.0f;
                b1[0] = (f16)r1; b1[1] = (f16)x1; b1[2] = (f16)y1; b1[3] = (f16)z1;
                b1[4] = (f16)i1; b1[5] = (f16)1.0f;
            } else {
                b0[0] = (f16)(a0 * tn); b0[1] = (f16)r0; b0[2] = (f16)x0; b0[3] = (f16)y0;
                b0[4] = (f16)z0; b0[5] = (f16)i0; b0[6] = (f16)1.0f;
                b1[0] = (f16)(a1 * tn); b1[1] = (f16)r1; b1[2] = (f16)x1; b1[3] = (f16)y1;
                b1[4] = (f16)z1; b1[5] = (f16)i1; b1[6] = (f16)1.0f;
            }
        }

        f32x4 acc[8][2];
        #pragma unroll
        for (int mt = 0; mt < 8; ++mt) {
            f16x8 a = *(const f16x8*)(lds_w + ((mt * 64 + lane) << 4));
            acc[mt][0] = mfma16(a, b0, z4);      // bin folded into A k=din slot
            acc[mt][1] = mfma16(a, b1, z4);
        }
        #pragma unroll
        for (int mt = 0; mt < 8; ++mt) {
            #pragma unroll
            for (int hh = 0; hh < 2; ++hh) {
                f32x4 v = acc[mt][hh];
                uint2 o;
                o.x = pk16(tanh_fast(v[0]), tanh_fast(v[1]));
                o.y = pk16(tanh_fast(v[2]), tanh_fast(v[3]));
                *(uint2*)(lds_h + waddr[mt] + hh * 4096) = o;
            }
        }

        // ---- 3 hidden layers, W staged in two 16 KB ks-halves ----
        for (int l = 0; l < 3; ++l) {
            const char* g = (const char*)(wb + WINA_ELEMS + l * WH_ELEMS);
            f32x4 bias4[8];
            #pragma unroll
            for (int half = 0; half < 2; ++half) {
                __syncthreads();          // lds_w readers done
                #pragma unroll
                for (int it = 0; it < 4; ++it)
                    stage16(g + half * 16384 + it * 4096 + tid * 16,
                            lds_w + it * 4096 + tid * 16);
                if (half == 0) {
                    // scaled bias loads complete during barrier's vmcnt drain
                    #pragma unroll
                    for (int mt = 0; mt < 8; ++mt)
                        bias4[mt] = *(const f32x4*)(bb + l * 128 + mt * 16 + q * 4);
                }
                __syncthreads();          // staged + H visible

                #pragma unroll
                for (int ks2 = 0; ks2 < 2; ++ks2) {
                    int ks = half * 2 + ks2;
                    f16x8 hb0 = *(const f16x8*)(lds_h + raddr[ks]);
                    f16x8 hb1 = *(const f16x8*)(lds_h + raddr[ks] + 4096);
                    #pragma unroll
                    for (int mt = 0; mt < 8; ++mt) {
                        f16x8 a = *(const f16x8*)(lds_w + (((ks2 * 8 + mt) * 64 + lane) << 4));
                        if (half == 0 && ks2 == 0) {
                            acc[mt][0] = mfma16(a, hb0, bias4[mt]);  // bias as C-init
                            acc[mt][1] = mfma16(a, hb1, bias4[mt]);
                        } else {
                            acc[mt][0] = mfma16(a, hb0, acc[mt][0]);
                            acc[mt][1] = mfma16(a, hb1, acc[mt][1]);
                        }
                    }
                }
            }
            #pragma unroll
            for (int mt = 0; mt < 8; ++mt) {
                #pragma unroll
                for (int hh = 0; hh < 2; ++hh) {
                    f32x4 v = acc[mt][hh];
                    uint2 o;
                    o.x = pk16(tanh_fast(v[0]), tanh_fast(v[1]));
                    o.y = pk16(tanh_fast(v[2]), tanh_fast(v[3]));
                    *(uint2*)(lds_h + waddr[mt] + hh * 4096) = o;
                }
            }
        }

        // ---- output layer: VALU dot, 2 threads per sample ----
        __syncthreads();                  // cross-lane H visibility
        {
            int s  = tid >> 1;
            int hf = tid & 1;
            const float* wp = Wout + hf * 64;
            float sum = 0.0f;
            #pragma unroll
            for (int u = 0; u < 8; ++u) {
                f16x8 hv = *(const f16x8*)(lds_h + h_addr(s, hf * 128 + u * 16));
                f32x4 w0 = *(const f32x4*)(wp + u * 8);
                f32x4 w1 = *(const f32x4*)(wp + u * 8 + 4);
                sum = fmaf((float)hv[0], w0[0], sum);
                sum = fmaf((float)hv[1], w0[1], sum);
                sum = fmaf((float)hv[2], w0[2], sum);
                sum = fmaf((float)hv[3], w0[3], sum);
                sum = fmaf((float)hv[4], w1[0], sum);
                sum = fmaf((float)hv[5], w1[1], sum);
                sum = fmaf((float)hv[6], w1[2], sum);
                sum = fmaf((float)hv[7], w1[3], sum);
            }
            sum += __shfl_xor(sum, 1, 64);
            float val = sum + bout[0];
            if (c == 0) icv = val;
            else        dsum = fmaf((c == 2) ? (8.0f / 9.0f) : (5.0f / 9.0f), val, dsum);
        }
    }

    if ((tid & 1) == 0) {
        out[p0 + (tid >> 1)] = (icv + ao * dsum) * io;
    }
}

extern "C" void kernel_launch(void* const* d_in, const int* in_sizes, int n_in,
                              void* d_out, int out_size, void* d_ws, size_t ws_size,
                              hipStream_t stream) {
    const float* tx      = (const float*)d_in[0];
    const float* dp_Win  = (const float*)d_in[1];
    const float* dp_bin  = (const float*)d_in[2];
    const float* dp_Wh   = (const float*)d_in[3];
    const float* dp_bh   = (const float*)d_in[4];
    const float* dp_Wout = (const float*)d_in[5];
    const float* dp_bout = (const float*)d_in[6];
    const float* ic_Win  = (const float*)d_in[7];
    const float* ic_bin  = (const float*)d_in[8];
    const float* ic_Wh   = (const float*)d_in[9];
    const float* ic_bh   = (const float*)d_in[10];
    const float* ic_Wout = (const float*)d_in[11];
    const float* ic_bout = (const float*)d_in[12];
    float* out = (float*)d_out;
    f16* wsw = (f16*)d_ws;

    int n = in_sizes[0] / 4;

    prep_kernel<<<dim3((2 * MLP_STRIDE + 768 + NTHREADS - 1) / NTHREADS), dim3(NTHREADS), 0, stream>>>(
        dp_Win, dp_bin, dp_Wh, dp_bh, ic_Win, ic_bin, ic_Wh, ic_bh, wsw);

    node_main<<<dim3(n / 128), dim3(NTHREADS), 0, stream>>>(
        tx, wsw, dp_Wout, dp_bout, ic_Wout, ic_bout, out);
}